// Round 1
// 1658.840 us; speedup vs baseline: 1.1518x; 1.1518x over previous
//
#include <hip/hip_runtime.h>
#include <hip/hip_bf16.h>
#include <cstdint>
#include <cstddef>

#define F_DIM 128
#define P_DIM 2048
#define RADIUS 4
#define HT_STRIDE 136   // ushorts per row: 272 B = 16B-aligned rows for b128 frag reads
#define LOG2E 1.4426950408889634f

typedef short s16x8 __attribute__((ext_vector_type(8)));
typedef float f32x4 __attribute__((ext_vector_type(4)));

static __device__ __forceinline__ float bf2f(ushort u) {
    union { float f; uint i; } v; v.i = ((uint)u) << 16; return v.f;
}
static __device__ __forceinline__ ushort f2bf(float f) {
    uint u = __float_as_uint(f);
    uint r = (u + 0x7fffu + ((u >> 16) & 1u)) >> 16;   // RTN-even
    return (ushort)r;
}
static __device__ __forceinline__ f32x4 mfma16(s16x8 a, s16x8 b, f32x4 c) {
    return __builtin_amdgcn_mfma_f32_16x16x32_bf16(a, b, c, 0, 0, 0);
}
// native v_exp_f32 / v_log_f32 (base-2). Args to ex2 are <= 0 after max-subtraction;
// flush-to-zero below 2^-126 matches softmax semantics (contribution ~0).
static __device__ __forceinline__ float ex2(float x) { return __builtin_amdgcn_exp2f(x); }
static __device__ __forceinline__ float lg2(float x) { return __builtin_amdgcn_logf(x); }

// ---------------- CSR build (once per launch) ----------------

__global__ void hist_kernel(const int* __restrict__ dst, int* __restrict__ counts, int E) {
    int e = blockIdx.x * blockDim.x + threadIdx.x;
    if (e < E) atomicAdd(&counts[dst[e]], 1);
}

__global__ __launch_bounds__(1024) void scan_kernel(const int* __restrict__ counts,
                                                    int* __restrict__ offs, int N) {
    __shared__ int buf[2][1024];
    __shared__ int carry_s;
    if (threadIdx.x == 0) carry_s = 0;
    __syncthreads();
    int nChunks = (N + 1023) >> 10;
    for (int c = 0; c < nChunks; ++c) {
        int i = (c << 10) + threadIdx.x;
        int v = (i < N) ? counts[i] : 0;
        int src = 0;
        buf[0][threadIdx.x] = v;
        __syncthreads();
        for (int off = 1; off < 1024; off <<= 1) {
            int d = src ^ 1;
            int val = buf[src][threadIdx.x];
            if (threadIdx.x >= (unsigned)off) val += buf[src][threadIdx.x - off];
            buf[d][threadIdx.x] = val;
            src = d;
            __syncthreads();
        }
        int inc = buf[src][threadIdx.x];
        if (i < N) offs[i + 1] = carry_s + inc;
        __syncthreads();
        if (threadIdx.x == 1023) carry_s += buf[src][1023];
        __syncthreads();
    }
    if (threadIdx.x == 0) offs[0] = 0;
}

__global__ void copy_kernel(const int* __restrict__ offs, int* __restrict__ cursor, int N) {
    int i = blockIdx.x * blockDim.x + threadIdx.x;
    if (i < N) cursor[i] = offs[i];
}

__global__ void scatter_kernel(const int* __restrict__ src, const int* __restrict__ dst,
                               int* __restrict__ cursor, int* __restrict__ srcs_sorted, int E) {
    int e = blockIdx.x * blockDim.x + threadIdx.x;
    if (e < E) {
        int d = dst[e];
        int pos = atomicAdd(&cursor[d], 1);
        srcs_sorted[pos] = src[e];
    }
}

// ---------------- one-time converts ----------------

__global__ void cvt_bf16_kernel(const float* __restrict__ src, ushort* __restrict__ dst, int n) {
    int i = blockIdx.x * blockDim.x + threadIdx.x;
    if (i < n) dst[i] = f2bf(src[i]);
}

__global__ void scale_kernel(const float* __restrict__ src, float* __restrict__ dst,
                             int n, float scale) {
    int i = blockIdx.x * blockDim.x + threadIdx.x;
    if (i < n) dst[i] = src[i] * scale;
}

// split fp32 W[K=128][P] (times scale) into hi+lo bf16, swizzled to MFMA B-frag order:
// dst[(((pt*4 + kt)*2 + s)*64 + lane)*8 + j] = split_s(scale*W[kt*32 + (lane>>4)*8 + j][pt*16 + (lane&15)])
__global__ void swizzle_split_kernel(const float* __restrict__ src, ushort* __restrict__ dst,
                                     int P, int total, float scale) {
    int d = blockIdx.x * blockDim.x + threadIdx.x;
    if (d >= total) return;
    int j    = d & 7;
    int lane = (d >> 3) & 63;
    int s    = (d >> 9) & 1;
    int kt   = (d >> 10) & 3;
    int pt   = d >> 12;
    int k = kt * 32 + (lane >> 4) * 8 + j;
    int p = pt * 16 + (lane & 15);
    float w = src[k * P + p] * scale;
    ushort hi = f2bf(w);
    ushort out = hi;
    if (s) out = f2bf(w - bf2f(hi));
    dst[d] = out;
}

// ---------------- aggregate (bf16 in, fp32 accum, bf16 out) ----------------
// 4 nodes per wave: quad q (16 lanes) owns one node; lane covers 16 B (uint4 = 8 bf16)
// of the 256 B row. 4 independent gather chains per wave -> 4x latency hiding and
// 1/4 the instructions vs the 1-node-per-wave version.

__global__ __launch_bounds__(256) void agg_kernel(const ushort* __restrict__ x,
                                                  const int* __restrict__ offs,
                                                  const int* __restrict__ srcs,
                                                  ushort* __restrict__ agg, int N) {
    int wid = (blockIdx.x * blockDim.x + threadIdx.x) >> 6;
    int lane = threadIdx.x & 63;
    int q = lane >> 4;
    int l16 = lane & 15;
    int node = wid * 4 + q;
    if (node >= N) return;
    const uint4* xr = (const uint4*)x;       // 16 uint4 per row
    uint4 v = xr[(size_t)node * 16 + l16];
    float acc[8];
    acc[0] = bf2f((ushort)(v.x & 0xffffu)); acc[1] = bf2f((ushort)(v.x >> 16));
    acc[2] = bf2f((ushort)(v.y & 0xffffu)); acc[3] = bf2f((ushort)(v.y >> 16));
    acc[4] = bf2f((ushort)(v.z & 0xffffu)); acc[5] = bf2f((ushort)(v.z >> 16));
    acc[6] = bf2f((ushort)(v.w & 0xffffu)); acc[7] = bf2f((ushort)(v.w >> 16));
    int e0 = offs[node], e1 = offs[node + 1];
    for (int e = e0; e < e1; ++e) {
        int j = srcs[e];
        uint4 u = xr[(size_t)j * 16 + l16];
        acc[0] += bf2f((ushort)(u.x & 0xffffu)); acc[1] += bf2f((ushort)(u.x >> 16));
        acc[2] += bf2f((ushort)(u.y & 0xffffu)); acc[3] += bf2f((ushort)(u.y >> 16));
        acc[4] += bf2f((ushort)(u.z & 0xffffu)); acc[5] += bf2f((ushort)(u.z >> 16));
        acc[6] += bf2f((ushort)(u.w & 0xffffu)); acc[7] += bf2f((ushort)(u.w >> 16));
    }
    uint4 o;
    o.x = ((uint)f2bf(acc[1]) << 16) | (uint)f2bf(acc[0]);
    o.y = ((uint)f2bf(acc[3]) << 16) | (uint)f2bf(acc[2]);
    o.z = ((uint)f2bf(acc[5]) << 16) | (uint)f2bf(acc[4]);
    o.w = ((uint)f2bf(acc[7]) << 16) | (uint)f2bf(acc[6]);
    ((uint4*)agg)[(size_t)node * 16 + l16] = o;
}

// ---------------- fused round ----------------
// block = 256 threads = 4 waves sharing ONE 64-node tile; wave w owns the P-range
// [32w, 32w+32). Barrier-free inner loops. NEW vs the 320us version: both lin2
// passes are software-pipelined one iteration deep:
//   * b-frags double-buffered in regs, iteration i+1's 8 loads issued ~1 full
//     iteration (~1000 cy) before first use -> L2 latency fully hidden;
//   * accumulators double-buffered (cA/cB); the online-softmax update consumes
//     the PREVIOUS iteration's c, so its ~115 VALU ops are independent of the
//     in-flight MFMAs and the scheduler can interleave them under MFMA issue.
// Numerically bit-identical to the unpipelined version (same op order per lane/j).
// Costs ~+32 VGPRs -> __launch_bounds__(256,2) (2 blocks/CU; each wave is now
// self-overlapping so occupancy matters less than stall removal).

#define LOADB(bb_) { _Pragma("unroll") for (int f = 0; f < 8; ++f) bb_[f] = wpn[f * 64]; wpn += 512; }

#define MFMA4(cc, bb_) { \
    _Pragma("unroll") for (int g = 0; g < 4; ++g) cc[g] = (f32x4){0.f, 0.f, 0.f, 0.f}; \
    _Pragma("unroll") for (int kt = 0; kt < 4; ++kt) { \
        _Pragma("unroll") for (int g = 0; g < 4; ++g) cc[g] = mfma16(a[g][kt], bb_[kt * 2 + 0], cc[g]); \
        _Pragma("unroll") for (int g = 0; g < 4; ++g) cc[g] = mfma16(a[g][kt], bb_[kt * 2 + 1], cc[g]); } }

#define P1_UPD4(cc, bbv) { \
    _Pragma("unroll") for (int g = 0; g < 4; ++g) \
    _Pragma("unroll") for (int r = 0; r < 4; ++r) { \
        int j = g * 4 + r; \
        float v = cc[g][r] + (bbv); \
        float d = v - m_[j]; \
        float e = ex2(-fabsf(d)); \
        float t1 = s_[j] + e; \
        float t2 = fmaf(s_[j], e, 1.0f); \
        bool up = d > 0.f; \
        s_[j] = up ? t2 : t1; \
        m_[j] = up ? v : m_[j]; } }

#define P2_UPD4(cc, bbv, ptv) { \
    float tot = 0.f; \
    _Pragma("unroll") for (int g = 0; g < 4; ++g) \
    _Pragma("unroll") for (int r = 0; r < 4; ++r) \
        tot += ex2(cc[g][r] + (bbv) + bbk[g * 4 + r]); \
    tot += __shfl_xor(tot, 16); \
    tot += __shfl_xor(tot, 32); \
    if (lane < 16) atomicAdd(&fp[(ptv) * 16 + lane], tot); }

__global__ __launch_bounds__(256, 2) void round_kernel(
        const ushort* __restrict__ agg,    // [N,128] bf16
        const ushort* __restrict__ w1sw,   // swizzled hi/lo bf16 (natural scale)
        const float*  __restrict__ b1,
        const ushort* __restrict__ w2sw,   // swizzled hi/lo bf16, scaled by log2e
        const float*  __restrict__ b2l,    // b2 * log2e
        ushort* __restrict__ h_out,        // [N,128] bf16 (next round x)
        float* __restrict__ fp,            // [2048]
        int N) {
    __shared__ ushort smem_u[64 * HT_STRIDE];  // 17.4 KB; hT, later (m,s) merge buf
    ushort* hT = smem_u;
    float* mbuf = (float*)smem_u;              // [64][4] after hT is dead
    float* sbuf = ((float*)smem_u) + 256;      // [64][4]

    const int tid = threadIdx.x;
    const int w = tid >> 6;
    const int lane = tid & 63;
    const int q = lane >> 4;
    const int l15 = lane & 15;
    const int nodeBase = blockIdx.x * 64;
    const int ptBase = w * 32;

    const s16x8* w1v = (const s16x8*)w1sw;   // frag index: (pt*8 + kt*2 + s)*64 + lane
    const s16x8* w2v = (const s16x8*)w2sw;

    // ---- A-frags from global agg (all 4 waves load the same tile; L1-served) ----
    s16x8 a[4][4];
    #pragma unroll
    for (int g = 0; g < 4; ++g) {
        int node = nodeBase + g * 16 + l15;
        #pragma unroll
        for (int kt = 0; kt < 4; ++kt) {
            if (node < N)
                a[g][kt] = *(const s16x8*)(agg + (size_t)node * F_DIM + kt * 32 + q * 8);
            else
                a[g][kt] = (s16x8){0, 0, 0, 0, 0, 0, 0, 0};
        }
    }

    // ---- lin1: wave w computes feature tiles 2w, 2w+1 (h = relu(agg@W1+b1)) ----
    #pragma unroll
    for (int t = 0; t < 2; ++t) {
        int pt = 2 * w + t;
        f32x4 c[4];
        #pragma unroll
        for (int g = 0; g < 4; ++g) c[g] = (f32x4){0.f, 0.f, 0.f, 0.f};
        const s16x8* wp = w1v + pt * 8 * 64;
        #pragma unroll
        for (int kt = 0; kt < 4; ++kt) {
            s16x8 bh = wp[(kt * 2 + 0) * 64 + lane];
            s16x8 bl = wp[(kt * 2 + 1) * 64 + lane];
            #pragma unroll
            for (int g = 0; g < 4; ++g) {
                c[g] = mfma16(a[g][kt], bh, c[g]);
                c[g] = mfma16(a[g][kt], bl, c[g]);
            }
        }
        float bb = b1[pt * 16 + l15];
        #pragma unroll
        for (int g = 0; g < 4; ++g)
            #pragma unroll
            for (int r = 0; r < 4; ++r) {
                float v = c[g][r] + bb;
                v = v > 0.f ? v : 0.f;
                hT[(g * 16 + q * 4 + r) * HT_STRIDE + pt * 16 + l15] = f2bf(v);
            }
    }
    __syncthreads();

    // ---- coalesced hT -> h_out: 64 rows x 16 chunks over 256 threads ----
    #pragma unroll
    for (int it = 0; it < 4; ++it) {
        int idx = it * 256 + tid;      // 0..1023
        int row = idx >> 4;            // 0..63
        int chunk = idx & 15;          // 0..15
        int gnode = nodeBase + row;
        if (gnode < N) {
            s16x8 vv = *(const s16x8*)&hT[row * HT_STRIDE + chunk * 8];
            *(s16x8*)(h_out + (size_t)gnode * F_DIM + chunk * 8) = vv;
        }
    }

    // ---- lin2 A-frags from hT (reuse a[][]) ----
    #pragma unroll
    for (int g = 0; g < 4; ++g)
        #pragma unroll
        for (int kt = 0; kt < 4; ++kt)
            a[g][kt] = *(const s16x8*)&hT[(g * 16 + l15) * HT_STRIDE + kt * 32 + q * 8];
    __syncthreads();   // hT dead everywhere; allow (m,s) overlay

    // ---- pass 1: online max / sum-exp2 over the wave's 32 pts (pipelined) ----
    float m_[16], s_[16];
    #pragma unroll
    for (int j = 0; j < 16; ++j) { m_[j] = -INFINITY; s_[j] = 0.f; }

    {
        const s16x8* wpn = w2v + ptBase * 8 * 64 + lane;   // bump by 512/LOADB
        const float* bpn = b2l + ptBase * 16 + l15;        // bump by 16/bias
        s16x8 bA[8], bB[8];
        f32x4 cA[4], cB[4];
        float bbA, bbB;
        LOADB(bA); bbA = *bpn; bpn += 16;   // i=0
        LOADB(bB); bbB = *bpn; bpn += 16;   // i=1
        MFMA4(cA, bA);                      // c(0)
        #pragma unroll 1
        for (int k = 0; k < 15; ++k) {
            // i = 2k+1: prefetch b(2k+2); compute c(2k+1); consume c(2k)
            float bbu = bbA;
            LOADB(bA); bbA = *bpn; bpn += 16;
            MFMA4(cB, bB);
            P1_UPD4(cA, bbu);
            // i = 2k+2: prefetch b(2k+3); compute c(2k+2); consume c(2k+1)
            float bbv = bbB;
            LOADB(bB); bbB = *bpn; bpn += 16;
            MFMA4(cA, bA);
            P1_UPD4(cB, bbv);
        }
        // i = 31: compute c(31); consume c(30), then c(31)
        MFMA4(cB, bB);
        P1_UPD4(cA, bbA);
        P1_UPD4(cB, bbB);
    }

    // ---- intra-wave merge across 16 p-lanes; publish per-wave partials ----
    #pragma unroll
    for (int j = 0; j < 16; ++j) {
        float mm = m_[j], ss = s_[j];
        #pragma unroll
        for (int off = 1; off <= 8; off <<= 1) {
            float om = __shfl_xor(mm, off);
            float os = __shfl_xor(ss, off);
            float nm = fmaxf(mm, om);
            ss = ss * ex2(mm - nm) + os * ex2(om - nm);
            mm = nm;
        }
        if (l15 == 0) {
            int node = (j >> 2) * 16 + q * 4 + (j & 3);
            mbuf[node * 4 + w] = mm;
            sbuf[node * 4 + w] = ss;
        }
    }
    __syncthreads();

    // ---- cross-wave merge -> bbk = -m - log2(s) ----
    float bbk[16];
    #pragma unroll
    for (int j = 0; j < 16; ++j) {
        int node = (j >> 2) * 16 + q * 4 + (j & 3);
        float4 mv = *(const float4*)&mbuf[node * 4];
        float4 sv = *(const float4*)&sbuf[node * 4];
        float nm = fmaxf(fmaxf(mv.x, mv.y), fmaxf(mv.z, mv.w));
        float ss = sv.x * ex2(mv.x - nm) + sv.y * ex2(mv.y - nm)
                 + sv.z * ex2(mv.z - nm) + sv.w * ex2(mv.w - nm);
        bbk[j] = (nodeBase + node < N) ? (-nm - lg2(ss)) : -INFINITY;
    }

    // ---- pass 2: recompute the wave's 32 pts (pipelined), atomics to global fp ----
    {
        const s16x8* wpn = w2v + ptBase * 8 * 64 + lane;
        const float* bpn = b2l + ptBase * 16 + l15;
        s16x8 bA[8], bB[8];
        f32x4 cA[4], cB[4];
        float bbA, bbB;
        LOADB(bA); bbA = *bpn; bpn += 16;   // i=0
        LOADB(bB); bbB = *bpn; bpn += 16;   // i=1
        MFMA4(cA, bA);                      // c(0)
        #pragma unroll 1
        for (int k = 0; k < 15; ++k) {
            float bbu = bbA;
            LOADB(bA); bbA = *bpn; bpn += 16;
            MFMA4(cB, bB);
            P2_UPD4(cA, bbu, ptBase + 2 * k);
            float bbv = bbB;
            LOADB(bB); bbB = *bpn; bpn += 16;
            MFMA4(cA, bA);
            P2_UPD4(cB, bbv, ptBase + 2 * k + 1);
        }
        MFMA4(cB, bB);
        P2_UPD4(cA, bbA, ptBase + 30);
        P2_UPD4(cB, bbB, ptBase + 31);
    }
}

// ---------------- launcher ----------------

extern "C" void kernel_launch(void* const* d_in, const int* in_sizes, int n_in,
                              void* d_out, int out_size, void* d_ws, size_t ws_size,
                              hipStream_t stream) {
    const float* atoms = (const float*)d_in[0];
    const float* W1    = (const float*)d_in[1];
    const float* b1    = (const float*)d_in[2];
    const float* W2    = (const float*)d_in[3];
    const float* b2    = (const float*)d_in[4];
    const int* esrc    = (const int*)d_in[5];
    const int* edst    = (const int*)d_in[6];
    float* fp          = (float*)d_out;
    const int N = in_sizes[0] / F_DIM;
    const int E = in_sizes[5];

    char* ws = (char*)d_ws;
    ushort* xA   = (ushort*)ws;  ws += (size_t)N * F_DIM * sizeof(ushort);
    ushort* xB   = (ushort*)ws;  ws += (size_t)N * F_DIM * sizeof(ushort);
    ushort* aggb = (ushort*)ws;  ws += (size_t)N * F_DIM * sizeof(ushort);
    ushort* w1sw = (ushort*)ws;  ws += (size_t)F_DIM * F_DIM * 2 * sizeof(ushort);
    ushort* w2sw = (ushort*)ws;  ws += (size_t)F_DIM * P_DIM * 2 * sizeof(ushort);
    float*  b2l  = (float*)ws;   ws += (size_t)P_DIM * sizeof(float);
    int* offs    = (int*)ws;     ws += (((size_t)(N + 1) * sizeof(int) + 255) & ~255ull);
    int* cursor  = (int*)ws;     ws += (((size_t)N * sizeof(int) + 255) & ~255ull);
    int* srcs    = (int*)ws;

    hipMemsetAsync(d_out, 0, (size_t)out_size * sizeof(float), stream);
    hipMemsetAsync(cursor, 0, (size_t)N * sizeof(int), stream);

    // CSR build
    int eb = (E + 255) / 256;
    hist_kernel<<<eb, 256, 0, stream>>>(edst, cursor, E);
    scan_kernel<<<1, 1024, 0, stream>>>(cursor, offs, N);
    copy_kernel<<<(N + 255) / 256, 256, 0, stream>>>(offs, cursor, N);
    scatter_kernel<<<eb, 256, 0, stream>>>(esrc, edst, cursor, srcs, E);

    // one-time converts
    int nconv = N * F_DIM;
    cvt_bf16_kernel<<<(nconv + 255) / 256, 256, 0, stream>>>(atoms, xA, nconv);
    int t1 = F_DIM * F_DIM * 2;
    swizzle_split_kernel<<<(t1 + 255) / 256, 256, 0, stream>>>(W1, w1sw, F_DIM, t1, 1.0f);
    int t2 = F_DIM * P_DIM * 2;
    swizzle_split_kernel<<<(t2 + 255) / 256, 256, 0, stream>>>(W2, w2sw, P_DIM, t2, LOG2E);
    scale_kernel<<<(P_DIM + 255) / 256, 256, 0, stream>>>(b2, b2l, P_DIM, LOG2E);

    const ushort* x = xA;
    ushort* xnext = xB;
    int rblocks = (N + 63) / 64;
    int ablocks = (N + 15) / 16;   // 16 nodes per 256-thread block (4/wave)
    for (int r = 0; r < RADIUS; ++r) {
        agg_kernel<<<ablocks, 256, 0, stream>>>(x, offs, srcs, aggb, N);
        round_kernel<<<rblocks, 256, 0, stream>>>(aggb, w1sw, b1, w2sw, b2l,
                                                  xnext, fp, N);
        x = xnext;
        xnext = (xnext == xB) ? xA : xB;
    }
}